// Round 4
// baseline (872.692 us; speedup 1.0000x reference)
//
#include <hip/hip_runtime.h>
#include <limits.h>

// Problem constants (from reference): C classes, N slots, D dims, B batch.
#define CC 1000
#define NN 256
#define DD 512
#define BB 4096
#define D4 (DD / 4)   // 128 float4 per row

typedef float f4 __attribute__((ext_vector_type(4)));

// ---------------------------------------------------------------------------
// Kernel 1: init last_pos[c] = -1 (workspace is re-poisoned each call, so we
// cannot rely on its previous contents; do not depend on the poison value).
// ---------------------------------------------------------------------------
__global__ void init_lastpos(int* last_pos) {
    int c = blockIdx.x * blockDim.x + threadIdx.x;
    if (c < CC) last_pos[c] = -1;
}

// ---------------------------------------------------------------------------
// Kernel 2: one WAVE per batch element. t = argmax(batch_targets[b,:]) with
// first-occurrence tie-break (jnp.argmax semantics); if selected and
// conf > confidences[t, N-1], atomicMax(&last_pos[t], b) == segment_max of
// last valid position per class.  Butterfly __shfl_xor reduce: no LDS, no
// __syncthreads.
// ---------------------------------------------------------------------------
__global__ void __launch_bounds__(256) push_kernel(
        const int* __restrict__ targets_mat,   // [B, C]
        const float* __restrict__ bconf,       // [B]
        const int* __restrict__ smask,         // [B]
        const float* __restrict__ conf,        // [C, N]
        int* __restrict__ last_pos) {          // [C]
    int wave = threadIdx.x >> 6;               // 0..3
    int lane = threadIdx.x & 63;
    int b = blockIdx.x * 4 + wave;
    const int* row = targets_mat + (size_t)b * CC;
    int bestv = INT_MIN, besti = 0;
    for (int i = lane; i < CC; i += 64) {      // coalesced: lanes read consecutive
        int v = row[i];
        // strictly-greater keeps first occurrence within a lane's rising i
        if (v > bestv) { bestv = v; besti = i; }
    }
    // 64-lane butterfly: max value, ties -> smaller index (assoc + commutative)
    for (int off = 32; off > 0; off >>= 1) {
        int ov = __shfl_xor(bestv, off);
        int oi = __shfl_xor(besti, off);
        if (ov > bestv || (ov == bestv && oi < besti)) { bestv = ov; besti = oi; }
    }
    if (lane == 0) {
        int t = besti;
        bool valid = (smask[b] != 0) && (bconf[b] > conf[(size_t)t * NN + (NN - 1)]);
        if (valid) atomicMax(&last_pos[t], b);
    }
}

// ---------------------------------------------------------------------------
// Kernel 3: per class, build the post-push confidence row, compute the stable
// descending rank of every slot (composite key: conf desc, idx asc — exactly
// jnp.argsort(-conf) stable), and emit src[c][pos] = source memory row for
// output position pos.  Negative value -(1+lp) encodes "batch_features[lp]".
// One 256-thread block per class; O(N^2)=65536 LDS-broadcast compares.
// NOTE: reference only replaces confidences[:, -1]; slots 0..N-2 keep their
// ORIGINAL (unshifted) confidences — keys below match that quirk exactly.
// ---------------------------------------------------------------------------
__global__ void __launch_bounds__(256) sort_kernel(
        const float* __restrict__ conf,        // [C, N]
        const float* __restrict__ bconf,       // [B]
        const int* __restrict__ last_pos,      // [C]
        int* __restrict__ src) {               // [C, N]
    int c = blockIdx.x;
    int tid = threadIdx.x;                     // slot index o = tid
    __shared__ float skey[NN];
    __shared__ int ssrc[NN];
    int lp = last_pos[c];
    bool updated = (lp >= 0);
    float key;
    if (tid == NN - 1)
        key = updated ? bconf[lp] : conf[(size_t)c * NN + (NN - 1)];
    else
        key = conf[(size_t)c * NN + tid];
    skey[tid] = key;
    __syncthreads();
    int rank = 0;
    for (int k = 0; k < NN; ++k) {
        float other = skey[k];                 // broadcast read, no bank conflict
        rank += (other > key || (other == key && k < tid)) ? 1 : 0;
    }
    // source row in original memory for this slot (after the shift-push)
    int s;
    if (updated) s = (tid == NN - 1) ? (-1 - lp) : (tid + 1);
    else         s = tid;
    ssrc[rank] = s;                            // ranks are a permutation
    __syncthreads();
    src[(size_t)c * NN + tid] = ssrc[tid];
}

// ---------------------------------------------------------------------------
// Kernel 4: gather — out[c, pos, :] = (s>=0) ? memory[c, s, :]
//                                            : batch_features[-1-s, :]
// Flat grid-stride permuted copy, the max-HBM-BW shape (m13 pattern):
//   - 2000 blocks x 256 threads = 512,000 threads; total 32,768,000 float4
//     = exactly 64 iterations/thread -> compile-time trip count, constant
//     stride, no bounds check: clean pipeline of independent load/store
//   - 16 B/lane coalesced on both streams
//   - nontemporal hints keep the two 524 MB streams from evicting the 1 MB
//     src table (L2-resident)
//   - #pragma unroll 4: 4 loads in flight per wave ahead of the stores
// ---------------------------------------------------------------------------
#define GATHER_BLOCKS 2000
#define GATHER_THREADS ((size_t)GATHER_BLOCKS * 256)   // 512,000
#define GATHER_ITERS 64                                // total / threads exactly

__global__ void __launch_bounds__(256) gather_kernel(
        const f4* __restrict__ mem4,           // [C*N*D4]
        const f4* __restrict__ feat4,          // [B*D4]
        const int* __restrict__ src,           // [C, N]
        f4* __restrict__ out4) {               // [C*N*D4]
    size_t idx = (size_t)blockIdx.x * blockDim.x + threadIdx.x;
    #pragma unroll 4
    for (int it = 0; it < GATHER_ITERS; ++it, idx += GATHER_THREADS) {
        int col = (int)(idx & (D4 - 1));       // float4 column within row
        size_t row = idx >> 7;                 // c*NN + j   (wave-uniform)
        int s = src[row];                      // broadcast, L2-hot
        const f4* sp = (s >= 0)
            ? (mem4 + (((row >> 8) << 8) + (size_t)s) * D4)   // (c*NN + s)*D4
            : (feat4 + (size_t)(-1 - s) * D4);
        f4 v = __builtin_nontemporal_load(sp + col);
        __builtin_nontemporal_store(v, out4 + idx);
    }
}

extern "C" void kernel_launch(void* const* d_in, const int* in_sizes, int n_in,
                              void* d_out, int out_size, void* d_ws, size_t ws_size,
                              hipStream_t stream) {
    const float* batch_features = (const float*)d_in[0];   // [B, D]
    const int*   batch_targets  = (const int*)d_in[1];     // [B, C]
    const float* batch_conf     = (const float*)d_in[2];   // [B]
    const int*   selected_mask  = (const int*)d_in[3];     // [B]
    const float* memory         = (const float*)d_in[4];   // [C, N, D]
    const float* confidences    = (const float*)d_in[5];   // [C, N]
    float* out = (float*)d_out;

    int* last_pos = (int*)d_ws;                // C ints
    int* src      = last_pos + CC;             // C*N ints

    init_lastpos<<<(CC + 255) / 256, 256, 0, stream>>>(last_pos);
    push_kernel<<<BB / 4, 256, 0, stream>>>(batch_targets, batch_conf,
                                            selected_mask, confidences, last_pos);
    sort_kernel<<<CC, 256, 0, stream>>>(confidences, batch_conf, last_pos, src);
    gather_kernel<<<GATHER_BLOCKS, 256, 0, stream>>>(
        (const f4*)memory, (const f4*)batch_features, src, (f4*)out);
}